// Round 8
// baseline (596.575 us; speedup 1.0000x reference)
//
#include <hip/hip_runtime.h>

// GAE: h1 = relu(spmm(X@W1)); h2 = relu(spmm(h1@W2)); Z = spmm(h2@W3);
// A = sigmoid(Z @ Z^T).  Outputs: [A (12288x12288), Z (12288x16)] fp32, concat.
//
// 4 dispatches: memset(cnt+bar+gen) -> [gemm1 || ELL-scatter] -> spmm_chain
// (3 layers, software grid barrier) -> decode_mfma.
// ELL edge buffer lives in the tail of A (decode overwrites it last).

constexpr int NN = 12288;   // nodes
constexpr int NE = 393216;  // edges
constexpr int KD = 1433;    // input dim
constexpr int CAP = 96;     // ELL row capacity (Poisson(32): P(deg>96) ~ 1e-18)

typedef float f32x4 __attribute__((ext_vector_type(4)));
typedef float f32x16 __attribute__((ext_vector_type(16)));
typedef short shortx8 __attribute__((ext_vector_type(8)));

// ---------------- fused: gemm1 (X@W1, LDS-tiled W) || ELL scatter ----------------
constexpr int KT = 256;
constexpr int G1B = NN / 64;  // 192 gemm blocks

__global__ __launch_bounds__(256) void k_scatter_gemm1(const int* __restrict__ er,
                                                       const int* __restrict__ ec,
                                                       const float* __restrict__ ev,
                                                       int* __restrict__ cnt,
                                                       uint2* __restrict__ ebuf,
                                                       const float* __restrict__ X,
                                                       const float* __restrict__ W,
                                                       float* __restrict__ out) {
    if (blockIdx.x >= G1B) {
        int e = (blockIdx.x - G1B) * 256 + threadIdx.x;
        int r = er[e];
        int p = atomicAdd(&cnt[r], 1);
        if (p < CAP) ebuf[(size_t)r * CAP + p] = make_uint2((unsigned)ec[e], __float_as_uint(ev[e]));
        return;
    }
    __shared__ float ws[KT * 32];
    int tid = threadIdx.x;
    int c4 = (tid & 7) * 4;
    int rs = tid >> 3;
    int r0 = blockIdx.x * 64 + rs;
    int r1 = r0 + 32;
    const float* x0 = X + (size_t)r0 * KD;
    const float* x1 = X + (size_t)r1 * KD;
    f32x4 acc0 = {0.f, 0.f, 0.f, 0.f};
    f32x4 acc1 = {0.f, 0.f, 0.f, 0.f};
    int phase = r0 & 3;
    int h = (4 - phase) & 3;

    for (int k0 = 0; k0 < KD; k0 += KT) {
        int kt = min(KT, KD - k0);
        __syncthreads();
        int n4 = (kt * 32) >> 2;
        for (int q = tid; q < n4; q += 256)
            *(f32x4*)(ws + q * 4) = *(const f32x4*)(W + (size_t)k0 * 32 + q * 4);
        __syncthreads();

        for (int kk = 0; kk < h; ++kk) {
            float a0 = x0[k0 + kk], a1 = x1[k0 + kk];
            const float* wr = ws + kk * 32 + c4;
#pragma unroll
            for (int j = 0; j < 4; ++j) { acc0[j] += a0 * wr[j]; acc1[j] += a1 * wr[j]; }
        }
        int nv = (kt - h) >> 2;
        const f32x4* p0 = (const f32x4*)(x0 + k0 + h);
        const f32x4* p1 = (const f32x4*)(x1 + k0 + h);
#pragma unroll 4
        for (int q = 0; q < nv; ++q) {
            f32x4 a0 = p0[q], a1 = p1[q];
            int kb = h + q * 4;
#pragma unroll
            for (int m = 0; m < 4; ++m) {
                f32x4 w4 = *(const f32x4*)(ws + (kb + m) * 32 + c4);
#pragma unroll
                for (int j = 0; j < 4; ++j) { acc0[j] += a0[m] * w4[j]; acc1[j] += a1[m] * w4[j]; }
            }
        }
        for (int kk = h + nv * 4; kk < kt; ++kk) {
            float a0 = x0[k0 + kk], a1 = x1[k0 + kk];
            const float* wr = ws + kk * 32 + c4;
#pragma unroll
            for (int j = 0; j < 4; ++j) { acc0[j] += a0 * wr[j]; acc1[j] += a1 * wr[j]; }
        }
    }
    *(f32x4*)(out + (size_t)r0 * 32 + c4) = acc0;
    *(f32x4*)(out + (size_t)r1 * 32 + c4) = acc1;
}

// ---------------- software grid barrier (256 co-resident blocks) ----------------
__device__ __forceinline__ void gsync(int* bar, int* gen) {
    __syncthreads();
    __threadfence();
    if (threadIdx.x == 0) {
        int g = __hip_atomic_load(gen, __ATOMIC_RELAXED, __HIP_MEMORY_SCOPE_AGENT);
        if (__hip_atomic_fetch_add(bar, 1, __ATOMIC_ACQ_REL, __HIP_MEMORY_SCOPE_AGENT) == (int)gridDim.x - 1) {
            __hip_atomic_store(bar, 0, __ATOMIC_RELAXED, __HIP_MEMORY_SCOPE_AGENT);
            __hip_atomic_fetch_add(gen, 1, __ATOMIC_ACQ_REL, __HIP_MEMORY_SCOPE_AGENT);
        } else {
            while (__hip_atomic_load(gen, __ATOMIC_ACQUIRE, __HIP_MEMORY_SCOPE_AGENT) == g)
                __builtin_amdgcn_s_sleep(16);
        }
    }
    __syncthreads();
    __threadfence();
}

// ---------------- spmm + relu + dense GEMM phase (device fn) ----------------
// 32 lanes per row; chunks of 4 edges via 2 broadcast uint4 loads.
template <int CO>
__device__ __forceinline__ void phase_spmm_gemm(const float* __restrict__ in,
                                                const float* __restrict__ Wm,
                                                float* __restrict__ out,
                                                const int* __restrict__ cnt,
                                                const uint2* __restrict__ ebuf) {
    int gid = blockIdx.x * 1024 + threadIdx.x;
    int c = gid & 31;
    int slot = gid >> 5;           // 8192 slots
    int lane = threadIdx.x & 63;
    int co = c & (CO - 1);
    float wcol[32];
#pragma unroll
    for (int k = 0; k < 32; ++k) wcol[k] = Wm[k * CO + co];
    for (int r = slot; r < NN; r += 8192) {
        int deg = min(cnt[r], CAP);
        const uint4* eb4 = (const uint4*)(ebuf + (size_t)r * CAP);
        const uint2* eb2 = (const uint2*)(ebuf + (size_t)r * CAP);
        float acc = 0.f;
        int i = 0;
        for (; i + 4 <= deg; i += 4) {
            uint4 e01 = eb4[i >> 1], e23 = eb4[(i >> 1) + 1];
            acc += __uint_as_float(e01.y) * in[(size_t)e01.x * 32 + c];
            acc += __uint_as_float(e01.w) * in[(size_t)e01.z * 32 + c];
            acc += __uint_as_float(e23.y) * in[(size_t)e23.x * 32 + c];
            acc += __uint_as_float(e23.w) * in[(size_t)e23.z * 32 + c];
        }
        for (; i < deg; ++i) {
            uint2 e = eb2[i];
            acc += __uint_as_float(e.y) * in[(size_t)e.x * 32 + c];
        }
        float h = fmaxf(acc, 0.f);
        float o = 0.f;
#pragma unroll
        for (int k = 0; k < 32; ++k)
            o += __shfl(h, (lane & 32) + k) * wcol[k];
        if (c < CO) out[(size_t)r * CO + co] = o;
    }
}

// ---------------- mega SpMM chain: 3 layers, 2 grid syncs ----------------
__global__ __launch_bounds__(1024) void spmm_chain(const float* __restrict__ t1,
                                                   const float* __restrict__ W2,
                                                   float* __restrict__ t2,
                                                   const float* __restrict__ W3,
                                                   float* __restrict__ t3,
                                                   float* __restrict__ Z,
                                                   unsigned short* __restrict__ Zb,
                                                   const int* __restrict__ cnt,
                                                   const uint2* __restrict__ ebuf,
                                                   int* bar, int* gen) {
    // P1: t2 = relu(spmm(t1)) @ W2
    phase_spmm_gemm<32>(t1, W2, t2, cnt, ebuf);
    gsync(bar, gen);
    // P2: t3 = relu(spmm(t2)) @ W3
    phase_spmm_gemm<16>(t2, W3, t3, cnt, ebuf);
    gsync(bar, gen);
    // P3: Z = spmm(t3); Zb = bf16(Z)
    int gid = blockIdx.x * 1024 + threadIdx.x;
    int c = gid & 15;
    int r = gid >> 4;              // 16384 slots >= NN
    if (r < NN) {
        int deg = min(cnt[r], CAP);
        const uint4* eb4 = (const uint4*)(ebuf + (size_t)r * CAP);
        const uint2* eb2 = (const uint2*)(ebuf + (size_t)r * CAP);
        float acc = 0.f;
        int i = 0;
        for (; i + 4 <= deg; i += 4) {
            uint4 e01 = eb4[i >> 1], e23 = eb4[(i >> 1) + 1];
            acc += __uint_as_float(e01.y) * t3[(size_t)e01.x * 16 + c];
            acc += __uint_as_float(e01.w) * t3[(size_t)e01.z * 16 + c];
            acc += __uint_as_float(e23.y) * t3[(size_t)e23.x * 16 + c];
            acc += __uint_as_float(e23.w) * t3[(size_t)e23.z * 16 + c];
        }
        for (; i < deg; ++i) {
            uint2 e = eb2[i];
            acc += __uint_as_float(e.y) * t3[(size_t)e.x * 16 + c];
        }
        Z[(size_t)r * 16 + c] = acc;
        unsigned int bits = __float_as_uint(acc);
        Zb[(size_t)r * 16 + c] = (unsigned short)((bits + 0x7FFFu + ((bits >> 16) & 1u)) >> 16);
    }
}

// ---------------- decode via MFMA: A = sigmoid(Zb @ Zb^T) ----------------
// 128x128 tile / 4 waves; wave = 64x64 quadrant = 4x mfma_f32_32x32x16_bf16.
// A-frag: row=l&31, k=(l>>5)*8+j.  B-frag: col=l&31, k=(l>>5)*8+j.
// D (m74-verified): col=l&31, row=(q&3)+8*(q>>2)+4*(l>>5), q=0..15.
__global__ __launch_bounds__(256) void decode_mfma(const unsigned short* __restrict__ Zb,
                                                   float* __restrict__ A) {
    int id = blockIdx.x;
    int f = (id & 7) * (9216 / 8) + (id >> 3);   // XCD swizzle (bijective: 9216%8==0)
    int bi = f / 96, bj = f % 96;
    int w = threadIdx.x >> 6;
    int l = threadIdx.x & 63;
    int R = bi * 128 + (w >> 1) * 64;
    int C = bj * 128 + (w & 1) * 64;
    int lr = l & 31, lh = l >> 5;

    shortx8 a0 = *(const shortx8*)(Zb + ((size_t)(R + lr) << 4) + lh * 8);
    shortx8 a1 = *(const shortx8*)(Zb + ((size_t)(R + 32 + lr) << 4) + lh * 8);
    shortx8 b0 = *(const shortx8*)(Zb + ((size_t)(C + lr) << 4) + lh * 8);
    shortx8 b1 = *(const shortx8*)(Zb + ((size_t)(C + 32 + lr) << 4) + lh * 8);

    f32x16 acc00 = {0.f}, acc01 = {0.f}, acc10 = {0.f}, acc11 = {0.f};
    acc00 = __builtin_amdgcn_mfma_f32_32x32x16_bf16(a0, b0, acc00, 0, 0, 0);
    acc01 = __builtin_amdgcn_mfma_f32_32x32x16_bf16(a0, b1, acc01, 0, 0, 0);
    acc10 = __builtin_amdgcn_mfma_f32_32x32x16_bf16(a1, b0, acc10, 0, 0, 0);
    acc11 = __builtin_amdgcn_mfma_f32_32x32x16_bf16(a1, b1, acc11, 0, 0, 0);

#pragma unroll
    for (int q = 0; q < 16; ++q) {
        int rf = (q & 3) + 8 * (q >> 2) + 4 * lh;
        float s00 = __fdividef(1.0f, 1.0f + __expf(-acc00[q]));
        float s01 = __fdividef(1.0f, 1.0f + __expf(-acc01[q]));
        float s10 = __fdividef(1.0f, 1.0f + __expf(-acc10[q]));
        float s11 = __fdividef(1.0f, 1.0f + __expf(-acc11[q]));
        __builtin_nontemporal_store(s00, &A[(size_t)(R + rf) * NN + C + lr]);
        __builtin_nontemporal_store(s01, &A[(size_t)(R + rf) * NN + C + 32 + lr]);
        __builtin_nontemporal_store(s10, &A[(size_t)(R + 32 + rf) * NN + C + lr]);
        __builtin_nontemporal_store(s11, &A[(size_t)(R + 32 + rf) * NN + C + 32 + lr]);
    }
}

extern "C" void kernel_launch(void* const* d_in, const int* in_sizes, int n_in,
                              void* d_out, int out_size, void* d_ws, size_t ws_size,
                              hipStream_t stream) {
    const float* X  = (const float*)d_in[0];
    const float* W1 = (const float*)d_in[1];
    const float* W2 = (const float*)d_in[2];
    const float* W3 = (const float*)d_in[3];
    const float* ev = (const float*)d_in[4];
    const int*   er = (const int*)d_in[5];
    const int*   ec = (const int*)d_in[6];

    float* A = (float*)d_out;                 // [NN, NN]
    float* Z = A + (size_t)NN * NN;           // [NN, 16]

    float* t1 = (float*)d_ws;                 // [NN, 32]  X@W1; later Zb (bf16)
    float* t2 = t1 + (size_t)NN * 32;         // [NN, 32]
    float* t3 = t2 + (size_t)NN * 32;         // [NN, 16]
    int*   cnt = (int*)(t3 + (size_t)NN * 16);  // [NN]
    int*   bar = cnt + NN;                    // [1]
    int*   gen = bar + 1;                     // [1]
    unsigned short* Zb = (unsigned short*)t1; // [NN, 16] bf16 (t1 dead by then)

    // ELL edge buffer in the tail of A (decode overwrites it last):
    // 9.4MB at 560MB offset; A is 604MB.
    uint2* ebuf = (uint2*)(A + (size_t)140000000);

    // zero cnt + barrier state (one tiny memset)
    (void)hipMemsetAsync(cnt, 0, (NN + 2) * sizeof(int), stream);

    // gemm1 (blocks 0..191) || ELL scatter (blocks 192..1727)
    k_scatter_gemm1<<<G1B + NE / 256, 256, 0, stream>>>(er, ec, ev, cnt, ebuf, X, W1, t1);

    // 3 SpMM layers in one kernel (256 blocks = 1/CU, co-resident; 2 grid syncs)
    spmm_chain<<<256, 1024, 0, stream>>>(t1, W2, t2, W3, t3, Z, Zb, cnt, ebuf, bar, gen);

    // A = sigmoid(Z @ Z^T) via MFMA
    decode_mfma<<<96 * 96, 256, 0, stream>>>(Zb, A);
}

// Round 9
// 264.192 us; speedup vs baseline: 2.2581x; 2.2581x over previous
//
#include <hip/hip_runtime.h>

// GAE: h1 = relu(spmm(X@W1)); h2 = relu(spmm(h1@W2)); Z = spmm(h2@W3);
// A = sigmoid(Z @ Z^T).  Outputs: [A (12288x12288), Z (12288x16)] fp32, concat.
//
// 6 dispatches: memset(cnt) -> [gemm1 || ELL-scatter] -> spmm+relu+@W2
//   -> spmm+relu+@W3 -> spmm16(+bf16) -> decode_mfma.
// ELL edge buffer lives in the tail of A (decode overwrites it last).

constexpr int NN = 12288;   // nodes
constexpr int NE = 393216;  // edges
constexpr int KD = 1433;    // input dim
constexpr int CAP = 96;     // ELL row capacity (Poisson(32): P(deg>96) ~ 1e-18)

typedef float f32x4 __attribute__((ext_vector_type(4)));
typedef float f32x16 __attribute__((ext_vector_type(16)));
typedef short shortx8 __attribute__((ext_vector_type(8)));

// ---------------- fused: gemm1 (X@W1, LDS-tiled W) || ELL scatter ----------------
constexpr int KT = 256;
constexpr int G1B = NN / 64;  // 192 gemm blocks

__global__ __launch_bounds__(256) void k_scatter_gemm1(const int* __restrict__ er,
                                                       const int* __restrict__ ec,
                                                       const float* __restrict__ ev,
                                                       int* __restrict__ cnt,
                                                       uint2* __restrict__ ebuf,
                                                       const float* __restrict__ X,
                                                       const float* __restrict__ W,
                                                       float* __restrict__ out) {
    if (blockIdx.x >= G1B) {
        int e = (blockIdx.x - G1B) * 256 + threadIdx.x;
        int r = er[e];
        int p = atomicAdd(&cnt[r], 1);
        if (p < CAP) ebuf[(size_t)r * CAP + p] = make_uint2((unsigned)ec[e], __float_as_uint(ev[e]));
        return;
    }
    __shared__ float ws[KT * 32];
    int tid = threadIdx.x;
    int c4 = (tid & 7) * 4;
    int rs = tid >> 3;
    int r0 = blockIdx.x * 64 + rs;
    int r1 = r0 + 32;
    const float* x0 = X + (size_t)r0 * KD;
    const float* x1 = X + (size_t)r1 * KD;
    f32x4 acc0 = {0.f, 0.f, 0.f, 0.f};
    f32x4 acc1 = {0.f, 0.f, 0.f, 0.f};
    int phase = r0 & 3;
    int h = (4 - phase) & 3;

    for (int k0 = 0; k0 < KD; k0 += KT) {
        int kt = min(KT, KD - k0);
        __syncthreads();
        int n4 = (kt * 32) >> 2;
        for (int q = tid; q < n4; q += 256)
            *(f32x4*)(ws + q * 4) = *(const f32x4*)(W + (size_t)k0 * 32 + q * 4);
        __syncthreads();

        for (int kk = 0; kk < h; ++kk) {
            float a0 = x0[k0 + kk], a1 = x1[k0 + kk];
            const float* wr = ws + kk * 32 + c4;
#pragma unroll
            for (int j = 0; j < 4; ++j) { acc0[j] += a0 * wr[j]; acc1[j] += a1 * wr[j]; }
        }
        int nv = (kt - h) >> 2;
        const f32x4* p0 = (const f32x4*)(x0 + k0 + h);
        const f32x4* p1 = (const f32x4*)(x1 + k0 + h);
#pragma unroll 4
        for (int q = 0; q < nv; ++q) {
            f32x4 a0 = p0[q], a1 = p1[q];
            int kb = h + q * 4;
#pragma unroll
            for (int m = 0; m < 4; ++m) {
                f32x4 w4 = *(const f32x4*)(ws + (kb + m) * 32 + c4);
#pragma unroll
                for (int j = 0; j < 4; ++j) { acc0[j] += a0[m] * w4[j]; acc1[j] += a1[m] * w4[j]; }
            }
        }
        for (int kk = h + nv * 4; kk < kt; ++kk) {
            float a0 = x0[k0 + kk], a1 = x1[k0 + kk];
            const float* wr = ws + kk * 32 + c4;
#pragma unroll
            for (int j = 0; j < 4; ++j) { acc0[j] += a0 * wr[j]; acc1[j] += a1 * wr[j]; }
        }
    }
    *(f32x4*)(out + (size_t)r0 * 32 + c4) = acc0;
    *(f32x4*)(out + (size_t)r1 * 32 + c4) = acc1;
}

// ---------------- SpMM(ELL) + relu + dense GEMM ----------------
// 32 lanes per row; 4-edge chunks via 2 broadcast uint4 loads, unroll 2
// (8 gathers in flight). Half-wave holds the full 32-chan row for the
// __shfl-based dense @Wm.
template <int CO>
__global__ __launch_bounds__(256) void spmm_gemm(const float* __restrict__ in,
                                                 const float* __restrict__ Wm,
                                                 float* __restrict__ out,
                                                 const int* __restrict__ cnt,
                                                 const uint2* __restrict__ ebuf) {
    int tid = blockIdx.x * 256 + threadIdx.x;
    int r = tid >> 5, c = tid & 31;
    int lane = threadIdx.x & 63;
    int co = c & (CO - 1);
    float wcol[32];
#pragma unroll
    for (int k = 0; k < 32; ++k) wcol[k] = Wm[k * CO + co];
    int deg = min(cnt[r], CAP);
    const uint4* eb4 = (const uint4*)(ebuf + (size_t)r * CAP);
    const uint2* eb2 = (const uint2*)(ebuf + (size_t)r * CAP);
    float acc = 0.f;
    int i = 0;
#pragma unroll 2
    for (; i + 4 <= deg; i += 4) {
        uint4 e01 = eb4[i >> 1], e23 = eb4[(i >> 1) + 1];
        acc += __uint_as_float(e01.y) * in[(size_t)e01.x * 32 + c];
        acc += __uint_as_float(e01.w) * in[(size_t)e01.z * 32 + c];
        acc += __uint_as_float(e23.y) * in[(size_t)e23.x * 32 + c];
        acc += __uint_as_float(e23.w) * in[(size_t)e23.z * 32 + c];
    }
    for (; i < deg; ++i) {
        uint2 e = eb2[i];
        acc += __uint_as_float(e.y) * in[(size_t)e.x * 32 + c];
    }
    float h = fmaxf(acc, 0.f);
    float o = 0.f;
#pragma unroll
    for (int k = 0; k < 32; ++k)
        o += __shfl(h, (lane & 32) + k) * wcol[k];
    if (c < CO) out[(size_t)r * CO + co] = o;
}

// ---------------- SpMM(ELL) width 16 -> Z (fp32) and Zb (bf16) ----------------
__global__ __launch_bounds__(256) void spmm16(const float* __restrict__ in,
                                              float* __restrict__ out,
                                              unsigned short* __restrict__ zb,
                                              const int* __restrict__ cnt,
                                              const uint2* __restrict__ ebuf) {
    int tid = blockIdx.x * 256 + threadIdx.x;
    int r = tid >> 4, c = tid & 15;
    int deg = min(cnt[r], CAP);
    const uint4* eb4 = (const uint4*)(ebuf + (size_t)r * CAP);
    const uint2* eb2 = (const uint2*)(ebuf + (size_t)r * CAP);
    float acc = 0.f;
    int i = 0;
#pragma unroll 2
    for (; i + 4 <= deg; i += 4) {
        uint4 e01 = eb4[i >> 1], e23 = eb4[(i >> 1) + 1];
        acc += __uint_as_float(e01.y) * in[(size_t)e01.x * 16 + c];
        acc += __uint_as_float(e01.w) * in[(size_t)e01.z * 16 + c];
        acc += __uint_as_float(e23.y) * in[(size_t)e23.x * 16 + c];
        acc += __uint_as_float(e23.w) * in[(size_t)e23.z * 16 + c];
    }
    for (; i < deg; ++i) {
        uint2 e = eb2[i];
        acc += __uint_as_float(e.y) * in[(size_t)e.x * 16 + c];
    }
    out[(size_t)r * 16 + c] = acc;
    unsigned int bits = __float_as_uint(acc);
    zb[(size_t)r * 16 + c] = (unsigned short)((bits + 0x7FFFu + ((bits >> 16) & 1u)) >> 16);
}

// ---------------- decode via MFMA: A = sigmoid(Zb @ Zb^T) ----------------
// 128x128 tile / 4 waves; wave = 64x64 quadrant = 4x mfma_f32_32x32x16_bf16.
// A-frag: row=l&31, k=(l>>5)*8+j.  B-frag: col=l&31, k=(l>>5)*8+j.
// D (m74-verified): col=l&31, row=(q&3)+8*(q>>2)+4*(l>>5), q=0..15.
__global__ __launch_bounds__(256) void decode_mfma(const unsigned short* __restrict__ Zb,
                                                   float* __restrict__ A) {
    int id = blockIdx.x;
    int f = (id & 7) * (9216 / 8) + (id >> 3);   // XCD swizzle (bijective: 9216%8==0)
    int bi = f / 96, bj = f % 96;
    int w = threadIdx.x >> 6;
    int l = threadIdx.x & 63;
    int R = bi * 128 + (w >> 1) * 64;
    int C = bj * 128 + (w & 1) * 64;
    int lr = l & 31, lh = l >> 5;

    shortx8 a0 = *(const shortx8*)(Zb + ((size_t)(R + lr) << 4) + lh * 8);
    shortx8 a1 = *(const shortx8*)(Zb + ((size_t)(R + 32 + lr) << 4) + lh * 8);
    shortx8 b0 = *(const shortx8*)(Zb + ((size_t)(C + lr) << 4) + lh * 8);
    shortx8 b1 = *(const shortx8*)(Zb + ((size_t)(C + 32 + lr) << 4) + lh * 8);

    f32x16 acc00 = {0.f}, acc01 = {0.f}, acc10 = {0.f}, acc11 = {0.f};
    acc00 = __builtin_amdgcn_mfma_f32_32x32x16_bf16(a0, b0, acc00, 0, 0, 0);
    acc01 = __builtin_amdgcn_mfma_f32_32x32x16_bf16(a0, b1, acc01, 0, 0, 0);
    acc10 = __builtin_amdgcn_mfma_f32_32x32x16_bf16(a1, b0, acc10, 0, 0, 0);
    acc11 = __builtin_amdgcn_mfma_f32_32x32x16_bf16(a1, b1, acc11, 0, 0, 0);

#pragma unroll
    for (int q = 0; q < 16; ++q) {
        int rf = (q & 3) + 8 * (q >> 2) + 4 * lh;
        float s00 = __fdividef(1.0f, 1.0f + __expf(-acc00[q]));
        float s01 = __fdividef(1.0f, 1.0f + __expf(-acc01[q]));
        float s10 = __fdividef(1.0f, 1.0f + __expf(-acc10[q]));
        float s11 = __fdividef(1.0f, 1.0f + __expf(-acc11[q]));
        __builtin_nontemporal_store(s00, &A[(size_t)(R + rf) * NN + C + lr]);
        __builtin_nontemporal_store(s01, &A[(size_t)(R + rf) * NN + C + 32 + lr]);
        __builtin_nontemporal_store(s10, &A[(size_t)(R + 32 + rf) * NN + C + lr]);
        __builtin_nontemporal_store(s11, &A[(size_t)(R + 32 + rf) * NN + C + 32 + lr]);
    }
}

extern "C" void kernel_launch(void* const* d_in, const int* in_sizes, int n_in,
                              void* d_out, int out_size, void* d_ws, size_t ws_size,
                              hipStream_t stream) {
    const float* X  = (const float*)d_in[0];
    const float* W1 = (const float*)d_in[1];
    const float* W2 = (const float*)d_in[2];
    const float* W3 = (const float*)d_in[3];
    const float* ev = (const float*)d_in[4];
    const int*   er = (const int*)d_in[5];
    const int*   ec = (const int*)d_in[6];

    float* A = (float*)d_out;                 // [NN, NN]
    float* Z = A + (size_t)NN * NN;           // [NN, 16]

    float* t1 = (float*)d_ws;                 // [NN, 32]  X@W1; later Zb (bf16)
    float* t2 = t1 + (size_t)NN * 32;         // [NN, 32]
    float* t3 = t2 + (size_t)NN * 32;         // [NN, 16]
    int*   cnt = (int*)(t3 + (size_t)NN * 16);  // [NN]
    unsigned short* Zb = (unsigned short*)t1; // [NN, 16] bf16 (t1 dead by then)

    // ELL edge buffer in the tail of A (decode overwrites it last):
    // 9.4MB at 560MB offset; A is 604MB.
    uint2* ebuf = (uint2*)(A + (size_t)140000000);

    (void)hipMemsetAsync(cnt, 0, NN * sizeof(int), stream);

    // gemm1 (blocks 0..191) || ELL scatter (blocks 192..1727)
    k_scatter_gemm1<<<G1B + NE / 256, 256, 0, stream>>>(er, ec, ev, cnt, ebuf, X, W1, t1);

    // t2 = relu(spmm(t1)) @ W2
    spmm_gemm<32><<<NN * 32 / 256, 256, 0, stream>>>(t1, W2, t2, cnt, ebuf);
    // t3 = relu(spmm(t2)) @ W3
    spmm_gemm<16><<<NN * 32 / 256, 256, 0, stream>>>(t2, W3, t3, cnt, ebuf);
    // Z = spmm(t3); Zb = bf16(Z)
    spmm16<<<NN * 16 / 256, 256, 0, stream>>>(t3, Z, Zb, cnt, ebuf);

    // A = sigmoid(Z @ Z^T) via MFMA
    decode_mfma<<<96 * 96, 256, 0, stream>>>(Zb, A);
}